// Round 1
// baseline (11348.491 us; speedup 1.0000x reference)
//
#include <hip/hip_runtime.h>

#define NN   30000
#define NE   480000
#define NR   7
#define NSEG (NN*NR)
#define DH   512
#define DIN  21
#define EPSB 1e-5f

static inline size_t align256(size_t x){ return (x + 255) & ~(size_t)255; }

// ---------------- CSR build (counting sort by seg = dst*7+rel) ----------------

__global__ void hist_k(const int* __restrict__ dst, const int* __restrict__ rel,
                       int* __restrict__ counts){
    int e = blockIdx.x*256 + threadIdx.x;
    if (e < NE) atomicAdd(&counts[dst[e]*NR + rel[e]], 1);
}

__global__ void scan1_k(const int* __restrict__ counts, int* __restrict__ bsum){
    __shared__ int sd[256];
    int t = threadIdx.x;
    int base = blockIdx.x*1024 + t*4;
    int s = 0;
#pragma unroll
    for (int i = 0; i < 4; i++){ int idx = base + i; if (idx < NSEG) s += counts[idx]; }
    sd[t] = s; __syncthreads();
    for (int off = 128; off > 0; off >>= 1){
        if (t < off) sd[t] += sd[t+off];
        __syncthreads();
    }
    if (t == 0) bsum[blockIdx.x] = sd[0];
}

__global__ void scan2_k(int* __restrict__ bsum, int nb, int* __restrict__ seg_start){
    __shared__ int sd[256];
    int t = threadIdx.x;
    int v = (t < nb) ? bsum[t] : 0;
    sd[t] = v; __syncthreads();
    for (int off = 1; off < 256; off <<= 1){
        int x = sd[t];
        if (t >= off) x += sd[t-off];
        __syncthreads();
        sd[t] = x; __syncthreads();
    }
    if (t < nb) bsum[t] = (t == 0) ? 0 : sd[t-1];
    if (t == 0) seg_start[NSEG] = NE;
}

__global__ void scan3_k(const int* __restrict__ counts, const int* __restrict__ bsum,
                        int* __restrict__ seg_start){
    __shared__ int sd[256];
    int t = threadIdx.x;
    int base = blockIdx.x*1024 + t*4;
    int v[4]; int s = 0;
#pragma unroll
    for (int i = 0; i < 4; i++){ int idx = base + i; v[i] = (idx < NSEG) ? counts[idx] : 0; s += v[i]; }
    sd[t] = s; __syncthreads();
    for (int off = 1; off < 256; off <<= 1){
        int x = sd[t];
        if (t >= off) x += sd[t-off];
        __syncthreads();
        sd[t] = x; __syncthreads();
    }
    int excl = sd[t] - s + bsum[blockIdx.x];
#pragma unroll
    for (int i = 0; i < 4; i++){
        int idx = base + i;
        if (idx < NSEG){ seg_start[idx] = excl; excl += v[i]; }
    }
}

__global__ void scatter_k(const int* __restrict__ src, const int* __restrict__ dst,
                          const int* __restrict__ rel, const int* __restrict__ seg_start,
                          int* __restrict__ cursor, int* __restrict__ src_sorted){
    int e = blockIdx.x*256 + threadIdx.x;
    if (e < NE){
        int s = dst[e]*NR + rel[e];
        int pos = seg_start[s] + atomicAdd(&cursor[s], 1);
        src_sorted[pos] = src[e];
    }
}

// ---------------- segment sums ----------------

// d=512: one block (128 thr, float4) per node; 7 relation rows accumulated in regs
__global__ void segsum512_k(const float* __restrict__ x, long xstride,
                            const int* __restrict__ seg_start, const int* __restrict__ src_sorted,
                            float* __restrict__ upd, int node0){
    int n = node0 + blockIdx.x;
    int t = threadIdx.x;
    float4 acc[NR];
#pragma unroll
    for (int r = 0; r < NR; r++) acc[r] = make_float4(0.f,0.f,0.f,0.f);
    int sb = n*NR;
    int e0 = seg_start[sb];
#pragma unroll
    for (int r = 0; r < NR; r++){
        int e1 = seg_start[sb + r + 1];
        for (int e = e0; e < e1; e++){
            int s = src_sorted[e];
            const float4* row = reinterpret_cast<const float4*>(x + (long)s*xstride);
            float4 v = row[t];
            acc[r].x += v.x; acc[r].y += v.y; acc[r].z += v.z; acc[r].w += v.w;
        }
        e0 = e1;
    }
    float4* o = reinterpret_cast<float4*>(upd + (long)blockIdx.x*(NR*DH));
#pragma unroll
    for (int r = 0; r < NR; r++) o[r*128 + t] = acc[r];
}

// d=21 (layer 0)
__global__ void segsum21_k(const float* __restrict__ x,
                           const int* __restrict__ seg_start, const int* __restrict__ src_sorted,
                           float* __restrict__ upd, int node0){
    int n = node0 + blockIdx.x;
    int t = threadIdx.x;
    if (t >= DIN) return;
    int sb = n*NR;
    float acc[NR];
#pragma unroll
    for (int r = 0; r < NR; r++) acc[r] = 0.f;
    int e0 = seg_start[sb];
#pragma unroll
    for (int r = 0; r < NR; r++){
        int e1 = seg_start[sb + r + 1];
        for (int e = e0; e < e1; e++)
            acc[r] += x[(long)src_sorted[e]*DIN + t];
        e0 = e1;
    }
#pragma unroll
    for (int r = 0; r < NR; r++)
        upd[(long)blockIdx.x*(NR*DIN) + r*DIN + t] = acc[r];
}

// ---------------- fp32 GEMM: C[M,512] (+)= A[M,K] @ W[512,K]^T + bias ----------------
// BM=64, BN=512 (A rows read exactly once), BK=16, 512 threads, 4x16 acc/thread.

template<int BETA>
__global__ __launch_bounds__(512)
void gemm_k(const float* __restrict__ A, long lda, int M,
            const float* __restrict__ W, int K,
            const float* __restrict__ bias,
            float* __restrict__ C){
    __shared__ float As[16][68];
    __shared__ float Ws[16][529];
    int bm = blockIdx.x*64;
    int t  = threadIdx.x;
    int tx = t & 31;      // column lane (cols j*32+tx)
    int ty = t >> 5;      // 0..15 row group (rows ty*4+i)
    float acc[4][16];
#pragma unroll
    for (int i = 0; i < 4; i++)
#pragma unroll
        for (int j = 0; j < 16; j++) acc[i][j] = 0.f;

    for (int k0 = 0; k0 < K; k0 += 16){
        // A tile: 64 x 16
#pragma unroll
        for (int rep = 0; rep < 2; rep++){
            int flat = rep*512 + t;
            int row = flat >> 4, kk = flat & 15;
            float v = 0.f;
            if (bm + row < M && k0 + kk < K) v = A[(long)(bm+row)*lda + k0 + kk];
            As[kk][row] = v;
        }
        // W tile: 512 x 16
#pragma unroll
        for (int rep = 0; rep < 16; rep++){
            int flat = rep*512 + t;
            int n = flat >> 4, kk = flat & 15;
            float v = 0.f;
            if (k0 + kk < K) v = W[(long)n*K + k0 + kk];
            Ws[kk][n] = v;
        }
        __syncthreads();
#pragma unroll
        for (int kk = 0; kk < 16; kk++){
            float a[4];
#pragma unroll
            for (int i = 0; i < 4; i++) a[i] = As[kk][ty*4 + i];
#pragma unroll
            for (int j = 0; j < 16; j++){
                float w = Ws[kk][j*32 + tx];
#pragma unroll
                for (int i = 0; i < 4; i++) acc[i][j] = fmaf(a[i], w, acc[i][j]);
            }
        }
        __syncthreads();
    }
#pragma unroll
    for (int i = 0; i < 4; i++){
        int row = bm + ty*4 + i;
        if (row < M){
#pragma unroll
            for (int j = 0; j < 16; j++){
                int col = j*32 + tx;
                float v = acc[i][j] + bias[col];
                long idx = (long)row*DH + col;
                if (BETA) v += C[idx];
                C[idx] = v;
            }
        }
    }
}

// ---------------- BatchNorm passes ----------------

__global__ void colstats_k(const float* __restrict__ buf, int M, float* __restrict__ sums){
    int col = blockIdx.x*256 + threadIdx.x;
    int r0 = blockIdx.y*512;
    int r1 = min(r0 + 512, M);
    float s = 0.f, s2 = 0.f;
    for (int r = r0; r < r1; r++){
        float v = buf[(long)r*DH + col];
        s += v; s2 = fmaf(v, v, s2);
    }
    atomicAdd(&sums[col], s);
    atomicAdd(&sums[DH + col], s2);
}

__global__ void finalize_k(const float* __restrict__ sums, const float* __restrict__ g,
                           const float* __restrict__ b, float* __restrict__ ac){
    int c = blockIdx.x*256 + threadIdx.x;
    if (c < DH){
        float mu  = sums[c] * (1.f/NN);
        float var = sums[DH + c] * (1.f/NN) - mu*mu;
        var = fmaxf(var, 0.f);
        float a = g[c] * rsqrtf(var + EPSB);
        ac[c]      = a;
        ac[DH + c] = fmaf(-mu, a, b[c]);
    }
}

__global__ void bnrelu_k(float* __restrict__ buf, int M, const float* __restrict__ ac,
                         float* __restrict__ sums2){
    int col = blockIdx.x*256 + threadIdx.x;
    int r0 = blockIdx.y*512;
    int r1 = min(r0 + 512, M);
    float a = ac[col], c = ac[DH + col];
    float s = 0.f, s2 = 0.f;
    for (int r = r0; r < r1; r++){
        long idx = (long)r*DH + col;
        float y = fmaxf(fmaf(a, buf[idx], c), 0.f);
        buf[idx] = y;
        s += y; s2 = fmaf(y, y, s2);
    }
    atomicAdd(&sums2[col], s);
    atomicAdd(&sums2[DH + col], s2);
}

__global__ void bn2write_k(const float* __restrict__ buf, const float* __restrict__ ac,
                           float* __restrict__ out, int layer){
    long i = (long)blockIdx.x*256 + threadIdx.x;
    if (i < (long)NN*DH){
        int r = (int)(i >> 9);
        int c = (int)(i & 511);
        out[(long)r*(3*DH) + layer*DH + c] = fmaf(ac[c], buf[i], ac[DH + c]);
    }
}

// ---------------- driver ----------------

extern "C" void kernel_launch(void* const* d_in, const int* in_sizes, int n_in,
                              void* d_out, int out_size, void* d_ws, size_t ws_size,
                              hipStream_t stream){
    const float* x0  = (const float*)d_in[0];
    const int*   src = (const int*)d_in[1];
    const int*   dst = (const int*)d_in[2];
    const int*   rel = (const int*)d_in[3];
    const float* lin_w[3]  = {(const float*)d_in[4],  (const float*)d_in[12], (const float*)d_in[20]};
    const float* self_w[3] = {(const float*)d_in[5],  (const float*)d_in[13], (const float*)d_in[21]};
    const float* lin_b[3]  = {(const float*)d_in[6],  (const float*)d_in[14], (const float*)d_in[22]};
    const float* self_b[3] = {(const float*)d_in[7],  (const float*)d_in[15], (const float*)d_in[23]};
    const float* bn1_g[3]  = {(const float*)d_in[8],  (const float*)d_in[16], (const float*)d_in[24]};
    const float* bn1_b[3]  = {(const float*)d_in[9],  (const float*)d_in[17], (const float*)d_in[25]};
    const float* bn2_g[3]  = {(const float*)d_in[10], (const float*)d_in[18], (const float*)d_in[26]};
    const float* bn2_b[3]  = {(const float*)d_in[11], (const float*)d_in[19], (const float*)d_in[27]};

    char* ws = (char*)d_ws;
    size_t off = 0;
    auto alloc = [&](size_t bytes)->char*{ char* p = ws + off; off = align256(off + bytes); return p; };

    int*   counts     = (int*)alloc((size_t)NSEG*4);
    int*   cursor     = (int*)alloc((size_t)NSEG*4);
    int*   seg_start  = (int*)alloc((size_t)(NSEG+1)*4);
    int*   bsum       = (int*)alloc(1024*4);
    int*   src_sorted = (int*)alloc((size_t)NE*4);
    float* stats      = (float*)alloc((size_t)8*DH*4);
    float* sums1 = stats;            float* sums2 = stats + 2*DH;
    float* ac1   = stats + 4*DH;     float* ac2   = stats + 6*DH;
    float* outbuf = (float*)alloc((size_t)NN*DH*4);

    // upd gets the remainder of the workspace; chunk nodes if it can't hold all.
    size_t remain = (ws_size > off) ? (ws_size - off) : 0;
    long max_nodes = (long)(remain / ((size_t)NR*DH*4));
    int chunk = (int)((max_nodes > NN) ? NN : max_nodes);
    chunk &= ~63;
    if (chunk < 64) chunk = 64;
    float* upd = (float*)(ws + off);

    // CSR build (once per launch; graph is layer-invariant)
    hipMemsetAsync(counts, 0, (size_t)NSEG*4, stream);
    hipMemsetAsync(cursor, 0, (size_t)NSEG*4, stream);
    hist_k<<<(NE+255)/256, 256, 0, stream>>>(dst, rel, counts);
    int nb = (NSEG + 1023)/1024;
    scan1_k<<<nb, 256, 0, stream>>>(counts, bsum);
    scan2_k<<<1, 256, 0, stream>>>(bsum, nb, seg_start);
    scan3_k<<<nb, 256, 0, stream>>>(counts, bsum, seg_start);
    scatter_k<<<(NE+255)/256, 256, 0, stream>>>(src, dst, rel, seg_start, cursor, src_sorted);

    for (int layer = 0; layer < 3; layer++){
        int d  = (layer == 0) ? DIN : DH;
        int Kl = NR*d;
        const float* xin = (layer == 0) ? x0 : ((const float*)d_out + (layer-1)*DH);
        long xstride     = (layer == 0) ? DIN : 3*DH;

        for (int c0 = 0; c0 < NN; c0 += chunk){
            int cn = (NN - c0 < chunk) ? (NN - c0) : chunk;
            if (layer == 0)
                segsum21_k<<<cn, 64, 0, stream>>>(xin, seg_start, src_sorted, upd, c0);
            else
                segsum512_k<<<cn, 128, 0, stream>>>(xin, xstride, seg_start, src_sorted, upd, c0);
            int gb = (cn + 63)/64;
            gemm_k<0><<<gb, 512, 0, stream>>>(upd, Kl, cn, lin_w[layer], Kl, lin_b[layer],
                                              outbuf + (long)c0*DH);
            gemm_k<1><<<gb, 512, 0, stream>>>(xin + (long)c0*xstride, xstride, cn,
                                              self_w[layer], d, self_b[layer],
                                              outbuf + (long)c0*DH);
        }

        hipMemsetAsync(stats, 0, (size_t)4*DH*4, stream);  // sums1 + sums2
        colstats_k<<<dim3(2, (NN+511)/512), 256, 0, stream>>>(outbuf, NN, sums1);
        finalize_k<<<2, 256, 0, stream>>>(sums1, bn1_g[layer], bn1_b[layer], ac1);
        bnrelu_k<<<dim3(2, (NN+511)/512), 256, 0, stream>>>(outbuf, NN, ac1, sums2);
        finalize_k<<<2, 256, 0, stream>>>(sums2, bn2_g[layer], bn2_b[layer], ac2);
        bn2write_k<<<((long)NN*DH + 255)/256, 256, 0, stream>>>(outbuf, ac2, (float*)d_out, layer);
    }
}

// Round 2
// 2045.919 us; speedup vs baseline: 5.5469x; 5.5469x over previous
//
#include <hip/hip_runtime.h>

#define NN   30000
#define NE   480000
#define NR   7
#define NSEG (NN*NR)
#define DH   512
#define DIN  21
#define EPSB 1e-5f
#define BK   32

typedef __attribute__((ext_vector_type(8))) short bf16x8;
typedef __attribute__((ext_vector_type(4))) float f32x4;
typedef unsigned short ushortT;

static inline size_t align256(size_t x){ return (x + 255) & ~(size_t)255; }

__device__ inline float bf2f(ushortT u){
    unsigned int i = ((unsigned int)u) << 16; float f; __builtin_memcpy(&f, &i, 4); return f;
}
__device__ inline ushortT f2bf(float f){
    unsigned int i; __builtin_memcpy(&i, &f, 4);
    unsigned int r = i + 0x7FFFu + ((i >> 16) & 1u);
    return (ushortT)(r >> 16);
}

__device__ inline void load_lds16(const ushortT* g, ushortT* l){
    __builtin_amdgcn_global_load_lds((const __attribute__((address_space(1))) unsigned int*)g,
                                     (__attribute__((address_space(3))) unsigned int*)l,
                                     16, 0, 0);
}

// ---------------- CSR build (counting sort by seg = dst*7+rel) ----------------

__global__ void hist_k(const int* __restrict__ dst, const int* __restrict__ rel,
                       int* __restrict__ counts){
    int e = blockIdx.x*256 + threadIdx.x;
    if (e < NE) atomicAdd(&counts[dst[e]*NR + rel[e]], 1);
}

__global__ void scan1_k(const int* __restrict__ counts, int* __restrict__ bsum){
    __shared__ int sd[256];
    int t = threadIdx.x;
    int base = blockIdx.x*1024 + t*4;
    int s = 0;
#pragma unroll
    for (int i = 0; i < 4; i++){ int idx = base + i; if (idx < NSEG) s += counts[idx]; }
    sd[t] = s; __syncthreads();
    for (int off = 128; off > 0; off >>= 1){
        if (t < off) sd[t] += sd[t+off];
        __syncthreads();
    }
    if (t == 0) bsum[blockIdx.x] = sd[0];
}

__global__ void scan2_k(int* __restrict__ bsum, int nb, int* __restrict__ seg_start){
    __shared__ int sd[256];
    int t = threadIdx.x;
    int v = (t < nb) ? bsum[t] : 0;
    sd[t] = v; __syncthreads();
    for (int off = 1; off < 256; off <<= 1){
        int x = sd[t];
        if (t >= off) x += sd[t-off];
        __syncthreads();
        sd[t] = x; __syncthreads();
    }
    if (t < nb) bsum[t] = (t == 0) ? 0 : sd[t-1];
    if (t == 0) seg_start[NSEG] = NE;
}

__global__ void scan3_k(const int* __restrict__ counts, const int* __restrict__ bsum,
                        int* __restrict__ seg_start){
    __shared__ int sd[256];
    int t = threadIdx.x;
    int base = blockIdx.x*1024 + t*4;
    int v[4]; int s = 0;
#pragma unroll
    for (int i = 0; i < 4; i++){ int idx = base + i; v[i] = (idx < NSEG) ? counts[idx] : 0; s += v[i]; }
    sd[t] = s; __syncthreads();
    for (int off = 1; off < 256; off <<= 1){
        int x = sd[t];
        if (t >= off) x += sd[t-off];
        __syncthreads();
        sd[t] = x; __syncthreads();
    }
    int excl = sd[t] - s + bsum[blockIdx.x];
#pragma unroll
    for (int i = 0; i < 4; i++){
        int idx = base + i;
        if (idx < NSEG){ seg_start[idx] = excl; excl += v[i]; }
    }
}

__global__ void scatter_k(const int* __restrict__ src, const int* __restrict__ dst,
                          const int* __restrict__ rel, const int* __restrict__ seg_start,
                          int* __restrict__ cursor, int* __restrict__ src_sorted){
    int e = blockIdx.x*256 + threadIdx.x;
    if (e < NE){
        int s = dst[e]*NR + rel[e];
        int pos = seg_start[s] + atomicAdd(&cursor[s], 1);
        src_sorted[pos] = src[e];
    }
}

// ---------------- segment sums → bf16 A rows (K-concat: [7d upd | d self]) ----------------

// layers 1,2: gather bf16 hidden rows (1KB), 128 threads × 4 cols
__global__ void segsum512b_k(const ushortT* __restrict__ hbf,
                             const int* __restrict__ seg_start, const int* __restrict__ src_sorted,
                             ushortT* __restrict__ Acat, int node0){
    int n = node0 + blockIdx.x;
    int t = threadIdx.x;
    ushortT* arow = Acat + (long)blockIdx.x*(8*DH);
    int sb = n*NR;
    int e0 = seg_start[sb];
#pragma unroll
    for (int r = 0; r < NR; r++){
        int e1 = seg_start[sb + r + 1];
        float a0=0.f, a1=0.f, a2=0.f, a3=0.f;
        for (int e = e0; e < e1; e++){
            const ushort4* row = reinterpret_cast<const ushort4*>(hbf + (long)src_sorted[e]*DH);
            ushort4 v = row[t];
            a0 += bf2f(v.x); a1 += bf2f(v.y); a2 += bf2f(v.z); a3 += bf2f(v.w);
        }
        e0 = e1;
        ushort4 o; o.x = f2bf(a0); o.y = f2bf(a1); o.z = f2bf(a2); o.w = f2bf(a3);
        reinterpret_cast<ushort4*>(arow + r*DH)[t] = o;
    }
    // self-loop columns
    reinterpret_cast<ushort4*>(arow + 7*DH)[t] =
        reinterpret_cast<const ushort4*>(hbf + (long)n*DH)[t];
}

// layer 0: d=21, Kp=192 (147 upd | 21 self | 24 pad)
__global__ void segsum21b_k(const float* __restrict__ x0,
                            const int* __restrict__ seg_start, const int* __restrict__ src_sorted,
                            ushortT* __restrict__ Acat, int node0){
    int n = node0 + blockIdx.x;
    int t = threadIdx.x;   // 64
    ushortT* arow = Acat + (long)blockIdx.x*192;
    if (t < DIN){
        int sb = n*NR;
        int e0 = seg_start[sb];
#pragma unroll
        for (int r = 0; r < NR; r++){
            int e1 = seg_start[sb + r + 1];
            float a = 0.f;
            for (int e = e0; e < e1; e++) a += x0[(long)src_sorted[e]*DIN + t];
            e0 = e1;
            arow[r*DIN + t] = f2bf(a);
        }
        arow[7*DIN + t] = f2bf(x0[(long)n*DIN + t]);
    }
    if (t >= 40) arow[168 + (t - 40)] = 0;   // zero pad cols 168..191
}

// ---------------- weight concat + bf16 convert: Wcat[512][Kp] ----------------

__global__ void convw_k(const float* __restrict__ lw, const float* __restrict__ sw,
                        int d, int Kp, ushortT* __restrict__ Wc){
    int i = blockIdx.x*256 + threadIdx.x;
    if (i < DH*Kp){
        int n = i / Kp, k = i % Kp;
        float v;
        if (k < 7*d)      v = lw[(long)n*7*d + k];
        else if (k < 8*d) v = sw[(long)n*d + (k - 7*d)];
        else              v = 0.f;
        Wc[i] = f2bf(v);
    }
}

// ---------------- bf16 MFMA GEMM: C[M,512] = A[M,Kp] @ W[512,Kp]^T + b1 + b2 ----------------
// 128x128 tile, BK=32, 256 thr (4 waves, 2x2 of 64x64), global_load_lds(16B), dbuf LDS.

__global__ __launch_bounds__(256)
void gemm_mfma_k(const ushortT* __restrict__ A, int lda, int M,
                 const ushortT* __restrict__ W,
                 const float* __restrict__ b1, const float* __restrict__ b2,
                 float* __restrict__ C, int nt){
    __shared__ ushortT As[2][128*BK];
    __shared__ ushortT Bs[2][128*BK];
    const int t    = threadIdx.x;
    const int bm   = blockIdx.x*128;
    const int bn   = blockIdx.y*128;
    const int w    = t >> 6;
    const int lane = t & 63;

    // staging map: 16B unit f = w*128 + i*64 + lane ; row=f>>2, kcol=(f&3)*8
    int f0 = w*128 + lane, f1 = f0 + 64;
    int ar0 = f0 >> 2, ac0 = (f0 & 3)*8;
    int ar1 = f1 >> 2, ac1 = (f1 & 3)*8;
    const ushortT* gA0 = A + (long)min(bm + ar0, M-1)*lda + ac0;
    const ushortT* gA1 = A + (long)min(bm + ar1, M-1)*lda + ac1;
    const ushortT* gB0 = W + (long)(bn + ar0)*lda + ac0;
    const ushortT* gB1 = W + (long)(bn + ar1)*lda + ac1;
    const int d0 = (w*128 +  0)*8;   // ushort offset of wave's LDS region
    const int d1 = (w*128 + 64)*8;

    f32x4 acc[4][4];
#pragma unroll
    for (int m = 0; m < 4; m++)
#pragma unroll
        for (int n = 0; n < 4; n++) acc[m][n] = (f32x4){0.f,0.f,0.f,0.f};

    const int wm = w >> 1, wn = w & 1;
    const int r = lane & 15, hi = lane >> 4;

    // prologue stage into buf 0
    load_lds16(gA0, &As[0][d0]);
    load_lds16(gA1, &As[0][d1]);
    load_lds16(gB0, &Bs[0][d0]);
    load_lds16(gB1, &Bs[0][d1]);

    for (int kt = 0; kt < nt; ++kt){
        __syncthreads();                       // buf[kt&1] staged, prev reads done
        if (kt + 1 < nt){
            int k0 = (kt + 1)*BK;
            int nb = (kt + 1) & 1;
            load_lds16(gA0 + k0, &As[nb][d0]);
            load_lds16(gA1 + k0, &As[nb][d1]);
            load_lds16(gB0 + k0, &Bs[nb][d0]);
            load_lds16(gB1 + k0, &Bs[nb][d1]);
        }
        int buf = kt & 1;
        bf16x8 af[4], bfr[4];
#pragma unroll
        for (int m = 0; m < 4; m++)
            af[m] = *reinterpret_cast<const bf16x8*>(&As[buf][(wm*64 + m*16 + r)*BK + hi*8]);
#pragma unroll
        for (int n = 0; n < 4; n++)
            bfr[n] = *reinterpret_cast<const bf16x8*>(&Bs[buf][(wn*64 + n*16 + r)*BK + hi*8]);
#pragma unroll
        for (int m = 0; m < 4; m++)
#pragma unroll
            for (int n = 0; n < 4; n++)
                acc[m][n] = __builtin_amdgcn_mfma_f32_16x16x32_bf16(af[m], bfr[n], acc[m][n], 0, 0, 0);
    }

#pragma unroll
    for (int m = 0; m < 4; m++){
        int row = bm + wm*64 + m*16 + hi*4;
#pragma unroll
        for (int n = 0; n < 4; n++){
            int col = bn + wn*64 + n*16 + r;
            float bias = b1[col] + b2[col];
#pragma unroll
            for (int q = 0; q < 4; q++){
                if (row + q < M) C[(long)(row + q)*DH + col] = acc[m][n][q] + bias;
            }
        }
    }
}

// ---------------- BatchNorm passes ----------------

__global__ void colstats_k(const float* __restrict__ buf, int M, float* __restrict__ sums){
    int col = blockIdx.x*256 + threadIdx.x;
    int r0 = blockIdx.y*512;
    int r1 = min(r0 + 512, M);
    float s = 0.f, s2 = 0.f;
    for (int r = r0; r < r1; r++){
        float v = buf[(long)r*DH + col];
        s += v; s2 = fmaf(v, v, s2);
    }
    atomicAdd(&sums[col], s);
    atomicAdd(&sums[DH + col], s2);
}

__global__ void finalize_k(const float* __restrict__ sums, const float* __restrict__ g,
                           const float* __restrict__ b, float* __restrict__ ac){
    int c = blockIdx.x*256 + threadIdx.x;
    if (c < DH){
        float mu  = sums[c] * (1.f/NN);
        float var = sums[DH + c] * (1.f/NN) - mu*mu;
        var = fmaxf(var, 0.f);
        float a = g[c] * rsqrtf(var + EPSB);
        ac[c]      = a;
        ac[DH + c] = fmaf(-mu, a, b[c]);
    }
}

__global__ void bnrelu_k(float* __restrict__ buf, int M, const float* __restrict__ ac,
                         float* __restrict__ sums2){
    int col = blockIdx.x*256 + threadIdx.x;
    int r0 = blockIdx.y*512;
    int r1 = min(r0 + 512, M);
    float a = ac[col], c = ac[DH + col];
    float s = 0.f, s2 = 0.f;
    for (int r = r0; r < r1; r++){
        long idx = (long)r*DH + col;
        float y = fmaxf(fmaf(a, buf[idx], c), 0.f);
        buf[idx] = y;
        s += y; s2 = fmaf(y, y, s2);
    }
    atomicAdd(&sums2[col], s);
    atomicAdd(&sums2[DH + col], s2);
}

__global__ void bn2write_k(const float* __restrict__ buf, const float* __restrict__ ac,
                           float* __restrict__ out, ushortT* __restrict__ hbf, int layer){
    long i = (long)blockIdx.x*256 + threadIdx.x;
    if (i < (long)NN*DH){
        int r = (int)(i >> 9);
        int c = (int)(i & 511);
        float h = fmaf(ac[c], buf[i], ac[DH + c]);
        out[(long)r*(3*DH) + layer*DH + c] = h;
        hbf[i] = f2bf(h);
    }
}

// ---------------- driver ----------------

extern "C" void kernel_launch(void* const* d_in, const int* in_sizes, int n_in,
                              void* d_out, int out_size, void* d_ws, size_t ws_size,
                              hipStream_t stream){
    const float* x0  = (const float*)d_in[0];
    const int*   src = (const int*)d_in[1];
    const int*   dst = (const int*)d_in[2];
    const int*   rel = (const int*)d_in[3];
    const float* lin_w[3]  = {(const float*)d_in[4],  (const float*)d_in[12], (const float*)d_in[20]};
    const float* self_w[3] = {(const float*)d_in[5],  (const float*)d_in[13], (const float*)d_in[21]};
    const float* lin_b[3]  = {(const float*)d_in[6],  (const float*)d_in[14], (const float*)d_in[22]};
    const float* self_b[3] = {(const float*)d_in[7],  (const float*)d_in[15], (const float*)d_in[23]};
    const float* bn1_g[3]  = {(const float*)d_in[8],  (const float*)d_in[16], (const float*)d_in[24]};
    const float* bn1_b[3]  = {(const float*)d_in[9],  (const float*)d_in[17], (const float*)d_in[25]};
    const float* bn2_g[3]  = {(const float*)d_in[10], (const float*)d_in[18], (const float*)d_in[26]};
    const float* bn2_b[3]  = {(const float*)d_in[11], (const float*)d_in[19], (const float*)d_in[27]};

    char* ws = (char*)d_ws;
    size_t off = 0;
    auto alloc = [&](size_t bytes)->char*{ char* p = ws + off; off = align256(off + bytes); return p; };

    int*     counts     = (int*)alloc((size_t)NSEG*4);
    int*     cursor     = (int*)alloc((size_t)NSEG*4);
    int*     seg_start  = (int*)alloc((size_t)(NSEG+1)*4);
    int*     bsum       = (int*)alloc(1024*4);
    int*     src_sorted = (int*)alloc((size_t)NE*4);
    float*   stats      = (float*)alloc((size_t)8*DH*4);
    float*   sums1 = stats;            float* sums2 = stats + 2*DH;
    float*   ac1   = stats + 4*DH;     float* ac2   = stats + 6*DH;
    float*   outbuf = (float*)alloc((size_t)NN*DH*4);
    ushortT* hbf    = (ushortT*)alloc((size_t)NN*DH*2);
    ushortT* Wcat   = (ushortT*)alloc((size_t)DH*4096*2);

    // Acat gets the remainder; chunk nodes if it can't hold all (8KB/row max).
    size_t remain = (ws_size > off) ? (ws_size - off) : 0;
    long max_nodes = (long)(remain / ((size_t)8*DH*2));
    int chunk = (int)((max_nodes > NN) ? NN : max_nodes);
    chunk &= ~127;
    if (chunk < 128) chunk = 128;
    ushortT* Acat = (ushortT*)(ws + off);

    // CSR build (graph is layer-invariant)
    hipMemsetAsync(counts, 0, (size_t)NSEG*4, stream);
    hipMemsetAsync(cursor, 0, (size_t)NSEG*4, stream);
    hist_k<<<(NE+255)/256, 256, 0, stream>>>(dst, rel, counts);
    int nb = (NSEG + 1023)/1024;
    scan1_k<<<nb, 256, 0, stream>>>(counts, bsum);
    scan2_k<<<1, 256, 0, stream>>>(bsum, nb, seg_start);
    scan3_k<<<nb, 256, 0, stream>>>(counts, bsum, seg_start);
    scatter_k<<<(NE+255)/256, 256, 0, stream>>>(src, dst, rel, seg_start, cursor, src_sorted);

    for (int layer = 0; layer < 3; layer++){
        int d  = (layer == 0) ? DIN : DH;
        int Kp = (layer == 0) ? 192 : 8*DH;     // 192 or 4096
        convw_k<<<(DH*Kp + 255)/256, 256, 0, stream>>>(lin_w[layer], self_w[layer], d, Kp, Wcat);

        for (int c0 = 0; c0 < NN; c0 += chunk){
            int cn = (NN - c0 < chunk) ? (NN - c0) : chunk;
            if (layer == 0)
                segsum21b_k<<<cn, 64, 0, stream>>>(x0, seg_start, src_sorted, Acat, c0);
            else
                segsum512b_k<<<cn, 128, 0, stream>>>(hbf, seg_start, src_sorted, Acat, c0);
            gemm_mfma_k<<<dim3((cn + 127)/128, 4), 256, 0, stream>>>(
                Acat, Kp, cn, Wcat, lin_b[layer], self_b[layer],
                outbuf + (long)c0*DH, Kp/BK);
        }

        hipMemsetAsync(stats, 0, (size_t)4*DH*4, stream);
        colstats_k<<<dim3(2, (NN+511)/512), 256, 0, stream>>>(outbuf, NN, sums1);
        finalize_k<<<2, 256, 0, stream>>>(sums1, bn1_g[layer], bn1_b[layer], ac1);
        bnrelu_k<<<dim3(2, (NN+511)/512), 256, 0, stream>>>(outbuf, NN, ac1, sums2);
        finalize_k<<<2, 256, 0, stream>>>(sums2, bn2_g[layer], bn2_b[layer], ac2);
        bn2write_k<<<((long)NN*DH + 255)/256, 256, 0, stream>>>(outbuf, ac2, (float*)d_out, hbf, layer);
    }
}

// Round 3
// 1637.755 us; speedup vs baseline: 6.9293x; 1.2492x over previous
//
#include <hip/hip_runtime.h>

#define NN   30000
#define NE   480000
#define NR   7
#define NSEG (NN*NR)
#define DH   512
#define DIN  21
#define EPSB 1e-5f
#define BK   32

typedef __attribute__((ext_vector_type(8))) short bf16x8;
typedef __attribute__((ext_vector_type(8))) unsigned short u16x8;
typedef __attribute__((ext_vector_type(4))) float f32x4;
typedef unsigned short ushortT;

static inline size_t align256(size_t x){ return (x + 255) & ~(size_t)255; }

__device__ inline float bf2f(ushortT u){
    unsigned int i = ((unsigned int)u) << 16; float f; __builtin_memcpy(&f, &i, 4); return f;
}
__device__ inline ushortT f2bf(float f){
    unsigned int i; __builtin_memcpy(&i, &f, 4);
    unsigned int r = i + 0x7FFFu + ((i >> 16) & 1u);
    return (ushortT)(r >> 16);
}

__device__ inline void load_lds16(const ushortT* g, ushortT* l){
    __builtin_amdgcn_global_load_lds((const __attribute__((address_space(1))) unsigned int*)g,
                                     (__attribute__((address_space(3))) unsigned int*)l,
                                     16, 0, 0);
}

// ---------------- CSR build (counting sort by seg = dst*7+rel) ----------------

__global__ void hist_k(const int* __restrict__ dst, const int* __restrict__ rel,
                       int* __restrict__ counts){
    int e = blockIdx.x*256 + threadIdx.x;
    if (e < NE) atomicAdd(&counts[dst[e]*NR + rel[e]], 1);
}

__global__ void scan1_k(const int* __restrict__ counts, int* __restrict__ bsum){
    __shared__ int sd[256];
    int t = threadIdx.x;
    int base = blockIdx.x*1024 + t*4;
    int s = 0;
#pragma unroll
    for (int i = 0; i < 4; i++){ int idx = base + i; if (idx < NSEG) s += counts[idx]; }
    sd[t] = s; __syncthreads();
    for (int off = 128; off > 0; off >>= 1){
        if (t < off) sd[t] += sd[t+off];
        __syncthreads();
    }
    if (t == 0) bsum[blockIdx.x] = sd[0];
}

__global__ void scan2_k(int* __restrict__ bsum, int nb, int* __restrict__ seg_start){
    __shared__ int sd[256];
    int t = threadIdx.x;
    int v = (t < nb) ? bsum[t] : 0;
    sd[t] = v; __syncthreads();
    for (int off = 1; off < 256; off <<= 1){
        int x = sd[t];
        if (t >= off) x += sd[t-off];
        __syncthreads();
        sd[t] = x; __syncthreads();
    }
    if (t < nb) bsum[t] = (t == 0) ? 0 : sd[t-1];
    if (t == 0) seg_start[NSEG] = NE;
}

__global__ void scan3_k(const int* __restrict__ counts, const int* __restrict__ bsum,
                        int* __restrict__ seg_start){
    __shared__ int sd[256];
    int t = threadIdx.x;
    int base = blockIdx.x*1024 + t*4;
    int v[4]; int s = 0;
#pragma unroll
    for (int i = 0; i < 4; i++){ int idx = base + i; v[i] = (idx < NSEG) ? counts[idx] : 0; s += v[i]; }
    sd[t] = s; __syncthreads();
    for (int off = 1; off < 256; off <<= 1){
        int x = sd[t];
        if (t >= off) x += sd[t-off];
        __syncthreads();
        sd[t] = x; __syncthreads();
    }
    int excl = sd[t] - s + bsum[blockIdx.x];
#pragma unroll
    for (int i = 0; i < 4; i++){
        int idx = base + i;
        if (idx < NSEG){ seg_start[idx] = excl; excl += v[i]; }
    }
}

__global__ void scatter_k(const int* __restrict__ src, const int* __restrict__ dst,
                          const int* __restrict__ rel, const int* __restrict__ seg_start,
                          int* __restrict__ cursor, int* __restrict__ src_sorted){
    int e = blockIdx.x*256 + threadIdx.x;
    if (e < NE){
        int s = dst[e]*NR + rel[e];
        int pos = seg_start[s] + atomicAdd(&cursor[s], 1);
        src_sorted[pos] = src[e];
    }
}

// ---------------- layer 0: segment sum d=21, Kp=192 (147 upd | 21 self | 24 pad) ----------------

__global__ void segsum21b_k(const float* __restrict__ x0,
                            const int* __restrict__ seg_start, const int* __restrict__ src_sorted,
                            ushortT* __restrict__ Acat){
    int n = blockIdx.x;
    int t = threadIdx.x;   // 64
    ushortT* arow = Acat + (long)n*192;
    if (t < DIN){
        int sb = n*NR;
        int e0 = seg_start[sb];
#pragma unroll
        for (int r = 0; r < NR; r++){
            int e1 = seg_start[sb + r + 1];
            float a = 0.f;
            for (int e = e0; e < e1; e++) a += x0[(long)src_sorted[e]*DIN + t];
            e0 = e1;
            arow[r*DIN + t] = f2bf(a);
        }
        arow[7*DIN + t] = f2bf(x0[(long)n*DIN + t]);
    }
    if (t >= 40) arow[168 + (t - 40)] = 0;   // zero pad cols 168..191
}

// ---------------- weight concat + bf16 convert: Wcat[512][Kp] ----------------

__global__ void convw_k(const float* __restrict__ lw, const float* __restrict__ sw,
                        int d, int Kp, ushortT* __restrict__ Wc){
    int i = blockIdx.x*256 + threadIdx.x;
    if (i < DH*Kp){
        int n = i / Kp, k = i % Kp;
        float v;
        if (k < 7*d)      v = lw[(long)n*7*d + k];
        else if (k < 8*d) v = sw[(long)n*d + (k - 7*d)];
        else              v = 0.f;
        Wc[i] = f2bf(v);
    }
}

// ---------------- layer-0 GEMM (128x128 tile, 4 waves) + fused col-stats ----------------

__global__ __launch_bounds__(256)
void gemm_mfma_k(const ushortT* __restrict__ A, int lda, int M,
                 const ushortT* __restrict__ W,
                 const float* __restrict__ b1, const float* __restrict__ b2,
                 float* __restrict__ C, int nt, float* __restrict__ sums){
    __shared__ ushortT As[2][128*BK];
    __shared__ ushortT Bs[2][128*BK];
    const int t    = threadIdx.x;
    const int bm   = blockIdx.x*128;
    const int bn   = blockIdx.y*128;
    const int w    = t >> 6;
    const int lane = t & 63;

    int f0 = w*128 + lane, f1 = f0 + 64;
    int ar0 = f0 >> 2, ac0 = (f0 & 3)*8;
    int ar1 = f1 >> 2, ac1 = (f1 & 3)*8;
    const ushortT* gA0 = A + (long)min(bm + ar0, M-1)*lda + ac0;
    const ushortT* gA1 = A + (long)min(bm + ar1, M-1)*lda + ac1;
    const ushortT* gB0 = W + (long)(bn + ar0)*lda + ac0;
    const ushortT* gB1 = W + (long)(bn + ar1)*lda + ac1;
    const int d0 = (w*128 +  0)*8;
    const int d1 = (w*128 + 64)*8;

    f32x4 acc[4][4];
#pragma unroll
    for (int m = 0; m < 4; m++)
#pragma unroll
        for (int n = 0; n < 4; n++) acc[m][n] = (f32x4){0.f,0.f,0.f,0.f};

    const int wm = w >> 1, wn = w & 1;
    const int r = lane & 15, hi = lane >> 4;

    load_lds16(gA0, &As[0][d0]);
    load_lds16(gA1, &As[0][d1]);
    load_lds16(gB0, &Bs[0][d0]);
    load_lds16(gB1, &Bs[0][d1]);

    for (int kt = 0; kt < nt; ++kt){
        __syncthreads();
        if (kt + 1 < nt){
            int k0 = (kt + 1)*BK;
            int nb = (kt + 1) & 1;
            load_lds16(gA0 + k0, &As[nb][d0]);
            load_lds16(gA1 + k0, &As[nb][d1]);
            load_lds16(gB0 + k0, &Bs[nb][d0]);
            load_lds16(gB1 + k0, &Bs[nb][d1]);
        }
        int buf = kt & 1;
        bf16x8 af[4], bfr[4];
#pragma unroll
        for (int m = 0; m < 4; m++)
            af[m] = *reinterpret_cast<const bf16x8*>(&As[buf][(wm*64 + m*16 + r)*BK + hi*8]);
#pragma unroll
        for (int n = 0; n < 4; n++)
            bfr[n] = *reinterpret_cast<const bf16x8*>(&Bs[buf][(wn*64 + n*16 + r)*BK + hi*8]);
#pragma unroll
        for (int m = 0; m < 4; m++)
#pragma unroll
            for (int n = 0; n < 4; n++)
                acc[m][n] = __builtin_amdgcn_mfma_f32_16x16x32_bf16(af[m], bfr[n], acc[m][n], 0, 0, 0);
    }

#pragma unroll
    for (int n = 0; n < 4; n++){
        int col = bn + wn*64 + n*16 + r;
        float bb = b1[col] + b2[col];
        float s = 0.f, s2 = 0.f;
#pragma unroll
        for (int m = 0; m < 4; m++){
            int row = bm + wm*64 + m*16 + hi*4;
#pragma unroll
            for (int q = 0; q < 4; q++){
                if (row + q < M){
                    float v = acc[m][n][q] + bb;
                    C[(long)(row + q)*DH + col] = v;
                    s += v; s2 = fmaf(v, v, s2);
                }
            }
        }
        s  += __shfl_xor(s, 16);  s  += __shfl_xor(s, 32);
        s2 += __shfl_xor(s2, 16); s2 += __shfl_xor(s2, 32);
        if (hi == 0){
            atomicAdd(&sums[col], s);
            atomicAdd(&sums[DH + col], s2);
        }
    }
}

// ---------------- fused gather-GEMM (layers 1,2) ----------------
// C[M,512] = [segsum(hbf) | hbf] @ Wcat[512,4096]^T + b1 + b2, full-width blocks.
// 128 rows x 512 cols per block, 8 waves (2Mx4N of 64x128), BK=32, K-tiles 0..127:
//   kt<112: rel = kt>>4, cols (kt&15)*32 — A-tile built by in-kernel segment-sum gather
//   kt>=112: self-loop copy from hbf.

__device__ inline u16x8 make_a_tile(int kt, int gnode, bool vnode, int tq,
                                    const ushortT* __restrict__ hbf,
                                    const int* __restrict__ seg_start,
                                    const int* __restrict__ src_sorted){
    u16x8 o;
    if (!vnode){
#pragma unroll
        for (int j = 0; j < 8; j++) o[j] = 0;
        return o;
    }
    if (kt >= 112){
        int c = ((kt - 112) << 5) + tq*8;
        return *reinterpret_cast<const u16x8*>(hbf + (long)gnode*DH + c);
    }
    int rel = kt >> 4;
    int c = ((kt & 15) << 5) + tq*8;
    int sb = gnode*NR + rel;
    int e0 = seg_start[sb], e1 = seg_start[sb + 1];
    float a[8];
#pragma unroll
    for (int j = 0; j < 8; j++) a[j] = 0.f;
    for (int e = e0; e < e1; e++){
        u16x8 v = *reinterpret_cast<const u16x8*>(hbf + (long)src_sorted[e]*DH + c);
#pragma unroll
        for (int j = 0; j < 8; j++) a[j] += bf2f((ushortT)v[j]);
    }
#pragma unroll
    for (int j = 0; j < 8; j++) o[j] = f2bf(a[j]);
    return o;
}

__global__ __launch_bounds__(512, 2)
void gemm_fused_k(const ushortT* __restrict__ hbf,
                  const int* __restrict__ seg_start, const int* __restrict__ src_sorted,
                  const ushortT* __restrict__ W,
                  const float* __restrict__ b1, const float* __restrict__ b2,
                  float* __restrict__ C, float* __restrict__ sums, int M){
    __shared__ ushortT As[2][128*BK];
    __shared__ ushortT Bs[2][512*BK];
    const int t = threadIdx.x;
    const int bm = blockIdx.x*128;
    const int w = t >> 6, lane = t & 63;
    const int wm = w >> 2, wn = w & 3;            // 2 x 4 wave grid
    const int r = lane & 15, hi = lane >> 4;
    const int trow = t >> 2, tq = t & 3;          // A-stage map: row, 8-col chunk
    const int gnode = bm + trow;
    const bool vnode = (gnode < M);

    const long woff = (long)(t >> 2)*4096 + (t & 3)*8;  // W elem offset for chunk f=t

    f32x4 acc[4][8];
#pragma unroll
    for (int m = 0; m < 4; m++)
#pragma unroll
        for (int n = 0; n < 8; n++) acc[m][n] = (f32x4){0.f,0.f,0.f,0.f};

    // prologue: stage kt=0 into buf 0
    {
#pragma unroll
        for (int i = 0; i < 4; i++)
            load_lds16(W + ((long)i*128)*4096 + woff, &Bs[0][(i*512 + t)*8]);
        u16x8 o = make_a_tile(0, gnode, vnode, tq, hbf, seg_start, src_sorted);
        *reinterpret_cast<u16x8*>(&As[0][t*8]) = o;
    }

    for (int kt = 0; kt < 128; ++kt){
        __syncthreads();
        const int buf = kt & 1;
        const bool more = (kt < 127);
        u16x8 onext;
        if (more){
            int k0 = (kt + 1)*BK;
#pragma unroll
            for (int i = 0; i < 4; i++)
                load_lds16(W + ((long)i*128)*4096 + woff + k0, &Bs[buf^1][(i*512 + t)*8]);
            onext = make_a_tile(kt + 1, gnode, vnode, tq, hbf, seg_start, src_sorted);
        }
        bf16x8 af[4], bfr[8];
#pragma unroll
        for (int m = 0; m < 4; m++)
            af[m] = *reinterpret_cast<const bf16x8*>(&As[buf][(wm*64 + m*16 + r)*BK + hi*8]);
#pragma unroll
        for (int n = 0; n < 8; n++)
            bfr[n] = *reinterpret_cast<const bf16x8*>(&Bs[buf][(wn*128 + n*16 + r)*BK + hi*8]);
#pragma unroll
        for (int m = 0; m < 4; m++)
#pragma unroll
            for (int n = 0; n < 8; n++)
                acc[m][n] = __builtin_amdgcn_mfma_f32_16x16x32_bf16(af[m], bfr[n], acc[m][n], 0, 0, 0);
        if (more)
            *reinterpret_cast<u16x8*>(&As[buf^1][t*8]) = onext;
    }

    // epilogue: bias + store + fused column stats
#pragma unroll
    for (int n = 0; n < 8; n++){
        int col = wn*128 + n*16 + r;
        float bb = b1[col] + b2[col];
        float s = 0.f, s2 = 0.f;
#pragma unroll
        for (int m = 0; m < 4; m++){
            int row = bm + wm*64 + m*16 + hi*4;
#pragma unroll
            for (int q = 0; q < 4; q++){
                if (row + q < M){
                    float v = acc[m][n][q] + bb;
                    C[(long)(row + q)*DH + col] = v;
                    s += v; s2 = fmaf(v, v, s2);
                }
            }
        }
        s  += __shfl_xor(s, 16);  s  += __shfl_xor(s, 32);
        s2 += __shfl_xor(s2, 16); s2 += __shfl_xor(s2, 32);
        if (hi == 0){
            atomicAdd(&sums[col], s);
            atomicAdd(&sums[DH + col], s2);
        }
    }
}

// ---------------- BatchNorm passes ----------------

__global__ void finalize_k(const float* __restrict__ sums, const float* __restrict__ g,
                           const float* __restrict__ b, float* __restrict__ ac){
    int c = blockIdx.x*256 + threadIdx.x;
    if (c < DH){
        float mu  = sums[c] * (1.f/NN);
        float var = sums[DH + c] * (1.f/NN) - mu*mu;
        var = fmaxf(var, 0.f);
        float a = g[c] * rsqrtf(var + EPSB);
        ac[c]      = a;
        ac[DH + c] = fmaf(-mu, a, b[c]);
    }
}

__global__ void bnrelu_k(float* __restrict__ buf, int M, const float* __restrict__ ac,
                         float* __restrict__ sums2){
    int col = blockIdx.x*256 + threadIdx.x;
    int r0 = blockIdx.y*512;
    int r1 = min(r0 + 512, M);
    float a = ac[col], c = ac[DH + col];
    float s = 0.f, s2 = 0.f;
    for (int r = r0; r < r1; r++){
        long idx = (long)r*DH + col;
        float y = fmaxf(fmaf(a, buf[idx], c), 0.f);
        buf[idx] = y;
        s += y; s2 = fmaf(y, y, s2);
    }
    atomicAdd(&sums2[col], s);
    atomicAdd(&sums2[DH + col], s2);
}

__global__ void bn2write_k(const float* __restrict__ buf, const float* __restrict__ ac,
                           float* __restrict__ out, ushortT* __restrict__ hbf, int layer){
    long i = (long)blockIdx.x*256 + threadIdx.x;
    if (i < (long)NN*DH){
        int r = (int)(i >> 9);
        int c = (int)(i & 511);
        float h = fmaf(ac[c], buf[i], ac[DH + c]);
        out[(long)r*(3*DH) + layer*DH + c] = h;
        hbf[i] = f2bf(h);
    }
}

// ---------------- driver ----------------

extern "C" void kernel_launch(void* const* d_in, const int* in_sizes, int n_in,
                              void* d_out, int out_size, void* d_ws, size_t ws_size,
                              hipStream_t stream){
    const float* x0  = (const float*)d_in[0];
    const int*   src = (const int*)d_in[1];
    const int*   dst = (const int*)d_in[2];
    const int*   rel = (const int*)d_in[3];
    const float* lin_w[3]  = {(const float*)d_in[4],  (const float*)d_in[12], (const float*)d_in[20]};
    const float* self_w[3] = {(const float*)d_in[5],  (const float*)d_in[13], (const float*)d_in[21]};
    const float* lin_b[3]  = {(const float*)d_in[6],  (const float*)d_in[14], (const float*)d_in[22]};
    const float* self_b[3] = {(const float*)d_in[7],  (const float*)d_in[15], (const float*)d_in[23]};
    const float* bn1_g[3]  = {(const float*)d_in[8],  (const float*)d_in[16], (const float*)d_in[24]};
    const float* bn1_b[3]  = {(const float*)d_in[9],  (const float*)d_in[17], (const float*)d_in[25]};
    const float* bn2_g[3]  = {(const float*)d_in[10], (const float*)d_in[18], (const float*)d_in[26]};
    const float* bn2_b[3]  = {(const float*)d_in[11], (const float*)d_in[19], (const float*)d_in[27]};

    char* ws = (char*)d_ws;
    size_t off = 0;
    auto alloc = [&](size_t bytes)->char*{ char* p = ws + off; off = align256(off + bytes); return p; };

    int*     counts     = (int*)alloc((size_t)NSEG*4);
    int*     cursor     = (int*)alloc((size_t)NSEG*4);
    int*     seg_start  = (int*)alloc((size_t)(NSEG+1)*4);
    int*     bsum       = (int*)alloc(1024*4);
    int*     src_sorted = (int*)alloc((size_t)NE*4);
    float*   stats      = (float*)alloc((size_t)8*DH*4);
    float*   sums1 = stats;            float* sums2 = stats + 2*DH;
    float*   ac1   = stats + 4*DH;     float* ac2   = stats + 6*DH;
    float*   outbuf = (float*)alloc((size_t)NN*DH*4);
    ushortT* hbf    = (ushortT*)alloc((size_t)NN*DH*2);
    ushortT* Wcat   = (ushortT*)alloc((size_t)DH*4096*2);
    ushortT* Acat0  = (ushortT*)alloc((size_t)NN*192*2);

    // CSR build (graph is layer-invariant)
    hipMemsetAsync(counts, 0, (size_t)NSEG*4, stream);
    hipMemsetAsync(cursor, 0, (size_t)NSEG*4, stream);
    hist_k<<<(NE+255)/256, 256, 0, stream>>>(dst, rel, counts);
    int nb = (NSEG + 1023)/1024;
    scan1_k<<<nb, 256, 0, stream>>>(counts, bsum);
    scan2_k<<<1, 256, 0, stream>>>(bsum, nb, seg_start);
    scan3_k<<<nb, 256, 0, stream>>>(counts, bsum, seg_start);
    scatter_k<<<(NE+255)/256, 256, 0, stream>>>(src, dst, rel, seg_start, cursor, src_sorted);

    const int MB = (NN + 127)/128;   // 235 row panels

    for (int layer = 0; layer < 3; layer++){
        int d  = (layer == 0) ? DIN : DH;
        int Kp = (layer == 0) ? 192 : 8*DH;
        convw_k<<<(DH*Kp + 255)/256, 256, 0, stream>>>(lin_w[layer], self_w[layer], d, Kp, Wcat);
        hipMemsetAsync(stats, 0, (size_t)4*DH*4, stream);   // sums1 + sums2

        if (layer == 0){
            segsum21b_k<<<NN, 64, 0, stream>>>(x0, seg_start, src_sorted, Acat0);
            gemm_mfma_k<<<dim3(MB, 4), 256, 0, stream>>>(
                Acat0, Kp, NN, Wcat, lin_b[layer], self_b[layer], outbuf, Kp/BK, sums1);
        } else {
            gemm_fused_k<<<MB, 512, 0, stream>>>(
                hbf, seg_start, src_sorted, Wcat, lin_b[layer], self_b[layer],
                outbuf, sums1, NN);
        }

        finalize_k<<<2, 256, 0, stream>>>(sums1, bn1_g[layer], bn1_b[layer], ac1);
        bnrelu_k<<<dim3(2, (NN+511)/512), 256, 0, stream>>>(outbuf, NN, ac1, sums2);
        finalize_k<<<2, 256, 0, stream>>>(sums2, bn2_g[layer], bn2_b[layer], ac2);
        bn2write_k<<<((long)NN*DH + 255)/256, 256, 0, stream>>>(outbuf, ac2, (float*)d_out, hbf, layer);
    }
}